// Round 11
// baseline (164.029 us; speedup 1.0000x reference)
//
#include <hip/hip_runtime.h>
#include <math.h>

#define Bn 8
#define Cc 512
#define HW 1024
#define HEADS 8
#define HD 64
#define GROUPS 32
#define CPG 16
#define EPS 1e-5f

typedef float f32x4 __attribute__((ext_vector_type(4)));
typedef __bf16 bf16x8 __attribute__((ext_vector_type(8)));
typedef __bf16 bf16x4 __attribute__((ext_vector_type(4)));
typedef short s16x4 __attribute__((ext_vector_type(4)));
typedef unsigned u32x2 __attribute__((ext_vector_type(2)));

__device__ __forceinline__ void async16(const __bf16* g, __bf16* l) {
    __builtin_amdgcn_global_load_lds((const __attribute__((address_space(1))) unsigned int*)g,
                                     (__attribute__((address_space(3))) unsigned int*)l, 16, 0, 0);
}

__device__ __forceinline__ f32x4 mfma16(bf16x4 a, bf16x4 b, f32x4 c) {
    return __builtin_amdgcn_mfma_f32_16x16x16bf16_1k(
        __builtin_bit_cast(s16x4, a), __builtin_bit_cast(s16x4, b), c, 0, 0, 0);
}

// pack hi16(f1):hi16(f0) via v_perm (bf16 truncation; p in [0,1], bias cancels in softmax)
__device__ __forceinline__ unsigned pk_bf16(float f1, float f0) {
    return __builtin_amdgcn_perm(__builtin_bit_cast(unsigned, f1),
                                 __builtin_bit_cast(unsigned, f0), 0x07060302u);
}

// ---------------- Merged: GroupNorm stats (blocks 0..255) + weight conversion (blocks 256+) ----
__global__ __launch_bounds__(256) void pre_kernel(const float* __restrict__ x,
                                                  float* __restrict__ gstats,
                                                  const float* __restrict__ wq,
                                                  __bf16* __restrict__ wq_bf,
                                                  const float* __restrict__ wp,
                                                  __bf16* __restrict__ wp_bf) {
    int blk = blockIdx.x;
    int tid = threadIdx.x;
    if (blk >= 256) {
        int i = (blk - 256) * 256 + tid;
        if (i < 196608) {
            float4 v = ((const float4*)wq)[i];
            bf16x4 o = { (__bf16)v.x, (__bf16)v.y, (__bf16)v.z, (__bf16)v.w };
            ((bf16x4*)wq_bf)[i] = o;
        } else {
            int j = i - 196608;
            float4 v = ((const float4*)wp)[j];
            bf16x4 o = { (__bf16)v.x, (__bf16)v.y, (__bf16)v.z, (__bf16)v.w };
            ((bf16x4*)wp_bf)[j] = o;
        }
        return;
    }
    int b = blk >> 5, g = blk & 31;
    const float* xp = x + ((size_t)b * Cc + g * CPG) * HW;
    float s = 0.f, ss = 0.f;
    for (int i = tid; i < CPG * HW; i += 256) {
        float v = xp[i];
        s += v; ss += v * v;
    }
    __shared__ float red0[4], red1[4];
    for (int off = 32; off > 0; off >>= 1) {
        s  += __shfl_down(s, off);
        ss += __shfl_down(ss, off);
    }
    int wave = tid >> 6, lane = tid & 63;
    if (lane == 0) { red0[wave] = s; red1[wave] = ss; }
    __syncthreads();
    if (tid == 0) {
        float S  = red0[0] + red0[1] + red0[2] + red0[3];
        float SS = red1[0] + red1[1] + red1[2] + red1[3];
        float mean = S / (float)(CPG * HW);
        float var  = SS / (float)(CPG * HW) - mean * mean;
        gstats[blk * 2]     = mean;
        gstats[blk * 2 + 1] = rsqrtf(var + EPS);
    }
}

// ---------------- GroupNorm apply -> hnT[b][n][c], fully coalesced writes ----------------
__global__ __launch_bounds__(256) void gn_apply(const float* __restrict__ x,
                                                const float* __restrict__ gamma,
                                                const float* __restrict__ beta,
                                                const float* __restrict__ gstats,
                                                __bf16* __restrict__ hnT) {
    int b = blockIdx.y, n0 = blockIdx.x * 32;
    __shared__ __align__(16) __bf16 T[32 * 520];
    __shared__ float gl[512], bl[512], sm[32], sr[32];
    int tid = threadIdx.x;
    if (tid < 32) {
        sm[tid] = gstats[(b * 32 + tid) * 2];
        sr[tid] = gstats[(b * 32 + tid) * 2 + 1];
    }
    for (int i = tid; i < 512; i += 256) { gl[i] = gamma[i]; bl[i] = beta[i]; }
    __syncthreads();
    const float* xb = x + (size_t)b * Cc * HW + n0;
    for (int i = tid; i < 16384; i += 256) {
        int c = i >> 5, n = i & 31;
        float v = xb[(size_t)c * HW + n];
        int g = c >> 4;
        T[n * 520 + c] = (__bf16)((v - sm[g]) * sr[g] * gl[c] + bl[c]);
    }
    __syncthreads();
    __bf16* hb = hnT + ((size_t)b * HW + n0) * Cc;
    for (int j = tid; j < 2048; j += 256) {
        int n = j >> 6, ch = j & 63;
        *(bf16x8*)&hb[(size_t)n * Cc + ch * 8] = *(const bf16x8*)&T[n * 520 + ch * 8];
    }
}

// ---------------- Fused QKV GEMM, m97-style 128x128 tiles ----------------
__global__ __launch_bounds__(256) void qkv_gemm(
    const __bf16* __restrict__ hnT, const __bf16* __restrict__ wq,
    const float* __restrict__ bias, __bf16* __restrict__ qkT,
    __bf16* __restrict__ vbuf, float scaleLo) {
    __shared__ __align__(16) __bf16 As[128 * 64];
    __shared__ __align__(16) __bf16 Bs[128 * 64];
    int tid = threadIdx.x;
    int wv = tid >> 6, lane = tid & 63, ln = lane & 15, quad = lane >> 4;
    int b = blockIdx.z;
    bool isQK = blockIdx.y < 8;
    int bm = (isQK ? blockIdx.y : blockIdx.y - 8) * 128;
    int bn = blockIdx.x * 128;
    const __bf16* hb = hnT + (size_t)b * HW * Cc;
    const __bf16* Pb = isQK ? hb : wq + (size_t)1024 * 512;
    const __bf16* Qb = isQK ? wq : hb;
    int wm = (wv >> 1) * 64, wn = (wv & 1) * 64;

    f32x4 acc[4][4];
    #pragma unroll
    for (int i = 0; i < 4; ++i)
        #pragma unroll
        for (int j = 0; j < 4; ++j) acc[i][j] = (f32x4){0.f, 0.f, 0.f, 0.f};

    for (int k0 = 0; k0 < 512; k0 += 64) {
        __syncthreads();
        #pragma unroll
        for (int u = 0; u < 4; ++u) {
            int idx = u * 256 + tid;
            int r = idx >> 3, lc = idx & 7;
            int cg = lc ^ (r & 7);
            async16(Pb + (size_t)(bm + r) * 512 + k0 + cg * 8, &As[r * 64 + lc * 8]);
            async16(Qb + (size_t)(bn + r) * 512 + k0 + cg * 8, &Bs[r * 64 + lc * 8]);
        }
        __syncthreads();
        bf16x8 af[4][2], bff[4][2];
        #pragma unroll
        for (int mt = 0; mt < 4; ++mt) {
            int row = wm + mt * 16 + ln;
            #pragma unroll
            for (int h = 0; h < 2; ++h) {
                int cc = (h * 4 + quad) ^ (ln & 7);
                af[mt][h] = *(const bf16x8*)&As[row * 64 + cc * 8];
            }
        }
        #pragma unroll
        for (int nt = 0; nt < 4; ++nt) {
            int row = wn + nt * 16 + ln;
            #pragma unroll
            for (int h = 0; h < 2; ++h) {
                int cc = (h * 4 + quad) ^ (ln & 7);
                bff[nt][h] = *(const bf16x8*)&Bs[row * 64 + cc * 8];
            }
        }
        #pragma unroll
        for (int mt = 0; mt < 4; ++mt)
            #pragma unroll
            for (int nt = 0; nt < 4; ++nt) {
                acc[mt][nt] = __builtin_amdgcn_mfma_f32_16x16x32_bf16(af[mt][0], bff[nt][0], acc[mt][nt], 0, 0, 0);
                acc[mt][nt] = __builtin_amdgcn_mfma_f32_16x16x32_bf16(af[mt][1], bff[nt][1], acc[mt][nt], 0, 0, 0);
            }
    }

    if (isQK) {
        __bf16* out = qkT + (size_t)b * HW * 1024;
        float bcol[4], scol[4];
        #pragma unroll
        for (int nt = 0; nt < 4; ++nt) {
            int col = bn + wn + nt * 16 + ln;
            bcol[nt] = bias[col];
            scol[nt] = (col < 512) ? scaleLo : 1.0f;
        }
        #pragma unroll
        for (int mt = 0; mt < 4; ++mt)
            #pragma unroll
            for (int r = 0; r < 4; ++r) {
                int row = bm + wm + mt * 16 + quad * 4 + r;
                #pragma unroll
                for (int nt = 0; nt < 4; ++nt) {
                    int col = bn + wn + nt * 16 + ln;
                    out[(size_t)row * 1024 + col] = (__bf16)((acc[mt][nt][r] + bcol[nt]) * scol[nt]);
                }
            }
    } else {
        __bf16* out = vbuf + (size_t)b * Cc * HW;
        #pragma unroll
        for (int mt = 0; mt < 4; ++mt)
            #pragma unroll
            for (int r = 0; r < 4; ++r) {
                int row = bm + wm + mt * 16 + quad * 4 + r;
                float brow = bias[1024 + row];
                #pragma unroll
                for (int nt = 0; nt < 4; ++nt) {
                    int col = bn + wn + nt * 16 + ln;
                    out[(size_t)row * 1024 + col] = (__bf16)(acc[mt][nt][r] + brow);
                }
            }
    }
}

// ---------------- proj GEMM 64x128 tiles with fp32 residual epilogue ----------------
__global__ __launch_bounds__(256) void proj_gemm(
    const __bf16* __restrict__ wp, const __bf16* __restrict__ attnT,
    const float* __restrict__ bias, const float* __restrict__ resid,
    float* __restrict__ outp) {
    __shared__ __align__(16) __bf16 As[64 * 64];
    __shared__ __align__(16) __bf16 Bs[128 * 64];
    int tid = threadIdx.x;
    int wv = tid >> 6, lane = tid & 63, ln = lane & 15, quad = lane >> 4;
    int b = blockIdx.z;
    int bm = blockIdx.y * 64, bn = blockIdx.x * 128;
    const __bf16* Qb = attnT + (size_t)b * HW * Cc;
    int wm = (wv >> 1) * 32, wn = (wv & 1) * 64;

    f32x4 acc[2][4];
    #pragma unroll
    for (int i = 0; i < 2; ++i)
        #pragma unroll
        for (int j = 0; j < 4; ++j) acc[i][j] = (f32x4){0.f, 0.f, 0.f, 0.f};

    for (int k0 = 0; k0 < 512; k0 += 64) {
        __syncthreads();
        #pragma unroll
        for (int u = 0; u < 2; ++u) {
            int idx = u * 256 + tid;
            int r = idx >> 3, lc = idx & 7;
            int cg = lc ^ (r & 7);
            async16(wp + (size_t)(bm + r) * 512 + k0 + cg * 8, &As[r * 64 + lc * 8]);
        }
        #pragma unroll
        for (int u = 0; u < 4; ++u) {
            int idx = u * 256 + tid;
            int r = idx >> 3, lc = idx & 7;
            int cg = lc ^ (r & 7);
            async16(Qb + (size_t)(bn + r) * 512 + k0 + cg * 8, &Bs[r * 64 + lc * 8]);
        }
        __syncthreads();
        bf16x8 af[2][2], bff[4][2];
        #pragma unroll
        for (int mt = 0; mt < 2; ++mt) {
            int row = wm + mt * 16 + ln;
            #pragma unroll
            for (int h = 0; h < 2; ++h) {
                int cc = (h * 4 + quad) ^ (ln & 7);
                af[mt][h] = *(const bf16x8*)&As[row * 64 + cc * 8];
            }
        }
        #pragma unroll
        for (int nt = 0; nt < 4; ++nt) {
            int row = wn + nt * 16 + ln;
            #pragma unroll
            for (int h = 0; h < 2; ++h) {
                int cc = (h * 4 + quad) ^ (ln & 7);
                bff[nt][h] = *(const bf16x8*)&Bs[row * 64 + cc * 8];
            }
        }
        #pragma unroll
        for (int mt = 0; mt < 2; ++mt)
            #pragma unroll
            for (int nt = 0; nt < 4; ++nt) {
                acc[mt][nt] = __builtin_amdgcn_mfma_f32_16x16x32_bf16(af[mt][0], bff[nt][0], acc[mt][nt], 0, 0, 0);
                acc[mt][nt] = __builtin_amdgcn_mfma_f32_16x16x32_bf16(af[mt][1], bff[nt][1], acc[mt][nt], 0, 0, 0);
            }
    }

    float* out = outp + (size_t)b * Cc * HW;
    const float* res = resid + (size_t)b * Cc * HW;
    #pragma unroll
    for (int mt = 0; mt < 2; ++mt)
        #pragma unroll
        for (int r = 0; r < 4; ++r) {
            int row = bm + wm + mt * 16 + quad * 4 + r;
            float bv = bias[row];
            #pragma unroll
            for (int nt = 0; nt < 4; ++nt) {
                int col = bn + wn + nt * 16 + ln;
                size_t idx = (size_t)row * 1024 + col;
                out[idx] = acc[mt][nt][r] + bv + res[idx];
            }
        }
}

// ---------------- Flash attention: 64 q/block, 1024 blocks (4/CU), 128 keys/barrier ----------------
// Grid (h=8, qb=16, b=8): idx%8 == h -> per-head XCD L2 locality.
// Max-free softmax: Q pre-scaled by 0.125*log2e; p = v_exp_f32(s); P packed via v_perm.
__global__ __launch_bounds__(256) void attn_mfma(const __bf16* __restrict__ qkT,
                                                 const __bf16* __restrict__ vbuf,
                                                 __bf16* __restrict__ attnT) {
    __shared__ __align__(16) __bf16 Ks[2][64 * 64];
    __shared__ __align__(16) __bf16 Vs[2][64 * 64];
    int tid = threadIdx.x;
    int wv = tid >> 6, lane = tid & 63, ln = lane & 15, quad = lane >> 4;
    int h = blockIdx.x, b = blockIdx.z;
    int i0 = blockIdx.y * 64 + wv * 16;

    const __bf16* qbase = qkT + ((size_t)b * HW + i0 + ln) * 1024 + h * HD + quad * 8;
    bf16x8 qf0 = *(const bf16x8*)qbase;
    bf16x8 qf1 = *(const bf16x8*)(qbase + 32);

    f32x4 oacc[4];
    #pragma unroll
    for (int ct = 0; ct < 4; ++ct) oacc[ct] = (f32x4){0.f, 0.f, 0.f, 0.f};
    float lsum = 0.f;

    for (int kt = 0; kt < 8; ++kt) {        // 8 barrier phases, 128 keys each
        __syncthreads();
        #pragma unroll
        for (int hh = 0; hh < 2; ++hh) {
            int kb = kt * 128 + hh * 64;
            #pragma unroll
            for (int u = 0; u < 2; ++u) {
                int idx = u * 256 + tid;
                int r = idx >> 3, lc = idx & 7;
                int cg = lc ^ (r & 7);
                async16(qkT + ((size_t)b * HW + kb + r) * 1024 + 512 + h * HD + cg * 8,
                        &Ks[hh][idx * 8]);
                async16(vbuf + ((size_t)b * Cc + h * HD + r) * HW + kb + cg * 8,
                        &Vs[hh][idx * 8]);
            }
        }
        __syncthreads();

        #pragma unroll
        for (int hh = 0; hh < 2; ++hh) {
            f32x4 st[4];
            #pragma unroll
            for (int jt = 0; jt < 4; ++jt) {
                int row = jt * 16 + ln;
                int c0 = quad ^ (ln & 7);
                int c1 = (4 + quad) ^ (ln & 7);
                bf16x8 kf0 = *(const bf16x8*)&Ks[hh][row * 64 + c0 * 8];
                bf16x8 kf1 = *(const bf16x8*)&Ks[hh][row * 64 + c1 * 8];
                f32x4 s = (f32x4){0.f, 0.f, 0.f, 0.f};
                s = __builtin_amdgcn_mfma_f32_16x16x32_bf16(kf0, qf0, s, 0, 0, 0);
                s = __builtin_amdgcn_mfma_f32_16x16x32_bf16(kf1, qf1, s, 0, 0, 0);
                st[jt] = s;
            }

            bf16x4 pk[4];
            #pragma unroll
            for (int jt = 0; jt < 4; ++jt) {
                float p0 = __builtin_amdgcn_exp2f(st[jt][0]);
                float p1 = __builtin_amdgcn_exp2f(st[jt][1]);
                float p2 = __builtin_amdgcn_exp2f(st[jt][2]);
                float p3 = __builtin_amdgcn_exp2f(st[jt][3]);
                lsum += (p0 + p1) + (p2 + p3);
                u32x2 w = { pk_bf16(p1, p0), pk_bf16(p3, p2) };
                pk[jt] = __builtin_bit_cast(bf16x4, w);
            }

            #pragma unroll
            for (int ct = 0; ct < 4; ++ct) {
                int row = ct * 16 + ln;
                bf16x4 vf[4];
                #pragma unroll
                for (int kss = 0; kss < 4; ++kss) {
                    int cc16 = (kss * 2 + (quad >> 1)) ^ (ln & 7);
                    vf[kss] = *(const bf16x4*)&Vs[hh][row * 64 + cc16 * 8 + (quad & 1) * 4];
                }
                #pragma unroll
                for (int kss = 0; kss < 4; ++kss)
                    oacc[ct] = mfma16(vf[kss], pk[kss], oacc[ct]);
            }
        }
    }

    lsum += __shfl_xor(lsum, 16);
    lsum += __shfl_xor(lsum, 32);
    float rl = 1.f / lsum;
    __bf16* op = attnT + ((size_t)b * HW + i0 + ln) * Cc + h * HD + quad * 4;
    #pragma unroll
    for (int ct = 0; ct < 4; ++ct) {
        bf16x4 o = { (__bf16)(oacc[ct][0] * rl), (__bf16)(oacc[ct][1] * rl),
                     (__bf16)(oacc[ct][2] * rl), (__bf16)(oacc[ct][3] * rl) };
        *(bf16x4*)(op + ct * 16) = o;
    }
}

extern "C" void kernel_launch(void* const* d_in, const int* in_sizes, int n_in,
                              void* d_out, int out_size, void* d_ws, size_t ws_size,
                              hipStream_t stream) {
    const float* x      = (const float*)d_in[0];
    const float* gamma  = (const float*)d_in[1];
    const float* beta   = (const float*)d_in[2];
    const float* w_qkv  = (const float*)d_in[3];
    const float* b_qkv  = (const float*)d_in[4];
    const float* w_proj = (const float*)d_in[5];
    const float* b_proj = (const float*)d_in[6];
    float* out = (float*)d_out;

    __bf16* wq_bf  = (__bf16*)d_ws;
    __bf16* wp_bf  = wq_bf + (size_t)1536 * 512;
    __bf16* hnT    = wp_bf + (size_t)512 * 512;
    __bf16* qkT    = hnT + (size_t)Bn * HW * Cc;
    __bf16* vbuf   = qkT + (size_t)Bn * HW * 1024;
    __bf16* attnT  = vbuf + (size_t)Bn * Cc * HW;
    float*  gstats = (float*)(attnT + (size_t)Bn * HW * Cc);

    pre_kernel<<<1280, 256, 0, stream>>>(x, gstats, w_qkv, wq_bf, w_proj, wp_bf);

    dim3 gga(32, Bn);
    gn_apply<<<gga, 256, 0, stream>>>(x, gamma, beta, gstats, hnT);

    const float QSCALE = 0.125f * 1.44269504088896f;  // hd^-0.5 * log2(e)
    dim3 gqkv(8, 12, Bn);
    qkv_gemm<<<gqkv, 256, 0, stream>>>(hnT, wq_bf, b_qkv, qkT, vbuf, QSCALE);

    dim3 ga(8, 16, 8);      // (h, qb, b): idx%8 == h -> per-head XCD locality; 4 blocks/CU
    attn_mfma<<<ga, 256, 0, stream>>>(qkT, vbuf, attnT);

    dim3 gp(8, 8, Bn);
    proj_gemm<<<gp, 256, 0, stream>>>(wp_bf, attnT, b_proj, x, out);
}

// Round 12
// 145.988 us; speedup vs baseline: 1.1236x; 1.1236x over previous
//
#include <hip/hip_runtime.h>
#include <math.h>

#define Bn 8
#define Cc 512
#define HW 1024
#define HEADS 8
#define HD 64
#define GROUPS 32
#define CPG 16
#define EPS 1e-5f

typedef float f32x4 __attribute__((ext_vector_type(4)));
typedef __bf16 bf16x8 __attribute__((ext_vector_type(8)));
typedef __bf16 bf16x4 __attribute__((ext_vector_type(4)));
typedef short s16x4 __attribute__((ext_vector_type(4)));
typedef unsigned u32x2 __attribute__((ext_vector_type(2)));

__device__ __forceinline__ void async16(const __bf16* g, __bf16* l) {
    __builtin_amdgcn_global_load_lds((const __attribute__((address_space(1))) unsigned int*)g,
                                     (__attribute__((address_space(3))) unsigned int*)l, 16, 0, 0);
}

__device__ __forceinline__ f32x4 mfma16(bf16x4 a, bf16x4 b, f32x4 c) {
    return __builtin_amdgcn_mfma_f32_16x16x16bf16_1k(
        __builtin_bit_cast(s16x4, a), __builtin_bit_cast(s16x4, b), c, 0, 0, 0);
}

// pack hi16(f1):hi16(f0) via v_perm (bf16 truncation; p in [0,1], bias cancels in softmax)
__device__ __forceinline__ unsigned pk_bf16(float f1, float f0) {
    return __builtin_amdgcn_perm(__builtin_bit_cast(unsigned, f1),
                                 __builtin_bit_cast(unsigned, f0), 0x07060302u);
}

// ---------------- Fused GroupNorm (blocks 0..255) + weight conversion (blocks 256+) ----------
// GN: one block per (b,g). Stage x-slice to LDS as bf16 while accumulating fp32 stats,
// then normalize+transpose-write hnT[b][n][g*16..] (32B/thread; ~2x write amp, no re-read).
__global__ __launch_bounds__(256) void gn_fused(const float* __restrict__ x,
                                                const float* __restrict__ gamma,
                                                const float* __restrict__ beta,
                                                __bf16* __restrict__ hnT,
                                                const float* __restrict__ wq,
                                                __bf16* __restrict__ wq_bf,
                                                const float* __restrict__ wp,
                                                __bf16* __restrict__ wp_bf) {
    int blk = blockIdx.x;
    int tid = threadIdx.x;
    if (blk >= 256) {
        int i = (blk - 256) * 256 + tid;
        if (i < 196608) {
            float4 v = ((const float4*)wq)[i];
            bf16x4 o = { (__bf16)v.x, (__bf16)v.y, (__bf16)v.z, (__bf16)v.w };
            ((bf16x4*)wq_bf)[i] = o;
        } else {
            int j = i - 196608;
            float4 v = ((const float4*)wp)[j];
            bf16x4 o = { (__bf16)v.x, (__bf16)v.y, (__bf16)v.z, (__bf16)v.w };
            ((bf16x4*)wp_bf)[j] = o;
        }
        return;
    }
    int b = blk >> 5, g = blk & 31;
    const float* xp = x + ((size_t)b * Cc + g * CPG) * HW;

    __shared__ __align__(16) __bf16 xs[16 * 1024];   // 32 KB
    __shared__ float red0[4], red1[4];
    __shared__ float gls[16], bls[16], stats[2];
    if (tid < 16) { gls[tid] = gamma[g * CPG + tid]; bls[tid] = beta[g * CPG + tid]; }

    float s = 0.f, ss = 0.f;
    for (int i4 = tid; i4 < 4096; i4 += 256) {
        float4 v = ((const float4*)xp)[i4];
        s  += (v.x + v.y) + (v.z + v.w);
        ss += (v.x * v.x + v.y * v.y) + (v.z * v.z + v.w * v.w);
        bf16x4 o = { (__bf16)v.x, (__bf16)v.y, (__bf16)v.z, (__bf16)v.w };
        ((bf16x4*)xs)[i4] = o;
    }
    for (int off = 32; off > 0; off >>= 1) {
        s  += __shfl_down(s, off);
        ss += __shfl_down(ss, off);
    }
    int wave = tid >> 6, lane = tid & 63;
    if (lane == 0) { red0[wave] = s; red1[wave] = ss; }
    __syncthreads();
    if (tid == 0) {
        float S  = red0[0] + red0[1] + red0[2] + red0[3];
        float SS = red1[0] + red1[1] + red1[2] + red1[3];
        float mean = S / (float)(CPG * HW);
        float var  = SS / (float)(CPG * HW) - mean * mean;
        stats[0] = mean;
        stats[1] = rsqrtf(var + EPS);
    }
    __syncthreads();
    float mean = stats[0], rstd = stats[1];
    #pragma unroll
    for (int u = 0; u < 4; ++u) {
        int n = tid + u * 256;
        union { __bf16 bs[16]; uint4 q[2]; } o;
        #pragma unroll
        for (int c = 0; c < 16; ++c) {
            float v = (float)xs[c * 1024 + n];
            o.bs[c] = (__bf16)((v - mean) * rstd * gls[c] + bls[c]);
        }
        uint4* dst = (uint4*)(hnT + ((size_t)b * HW + n) * Cc + g * CPG);
        dst[0] = o.q[0];
        dst[1] = o.q[1];
    }
}

// ---------------- Fused QKV GEMM, m97-style 128x128 tiles ----------------
__global__ __launch_bounds__(256) void qkv_gemm(
    const __bf16* __restrict__ hnT, const __bf16* __restrict__ wq,
    const float* __restrict__ bias, __bf16* __restrict__ qkT,
    __bf16* __restrict__ vbuf, float scaleLo) {
    __shared__ __align__(16) __bf16 As[128 * 64];
    __shared__ __align__(16) __bf16 Bs[128 * 64];
    int tid = threadIdx.x;
    int wv = tid >> 6, lane = tid & 63, ln = lane & 15, quad = lane >> 4;
    int b = blockIdx.z;
    bool isQK = blockIdx.y < 8;
    int bm = (isQK ? blockIdx.y : blockIdx.y - 8) * 128;
    int bn = blockIdx.x * 128;
    const __bf16* hb = hnT + (size_t)b * HW * Cc;
    const __bf16* Pb = isQK ? hb : wq + (size_t)1024 * 512;
    const __bf16* Qb = isQK ? wq : hb;
    int wm = (wv >> 1) * 64, wn = (wv & 1) * 64;

    f32x4 acc[4][4];
    #pragma unroll
    for (int i = 0; i < 4; ++i)
        #pragma unroll
        for (int j = 0; j < 4; ++j) acc[i][j] = (f32x4){0.f, 0.f, 0.f, 0.f};

    for (int k0 = 0; k0 < 512; k0 += 64) {
        __syncthreads();
        #pragma unroll
        for (int u = 0; u < 4; ++u) {
            int idx = u * 256 + tid;
            int r = idx >> 3, lc = idx & 7;
            int cg = lc ^ (r & 7);
            async16(Pb + (size_t)(bm + r) * 512 + k0 + cg * 8, &As[r * 64 + lc * 8]);
            async16(Qb + (size_t)(bn + r) * 512 + k0 + cg * 8, &Bs[r * 64 + lc * 8]);
        }
        __syncthreads();
        bf16x8 af[4][2], bff[4][2];
        #pragma unroll
        for (int mt = 0; mt < 4; ++mt) {
            int row = wm + mt * 16 + ln;
            #pragma unroll
            for (int h = 0; h < 2; ++h) {
                int cc = (h * 4 + quad) ^ (ln & 7);
                af[mt][h] = *(const bf16x8*)&As[row * 64 + cc * 8];
            }
        }
        #pragma unroll
        for (int nt = 0; nt < 4; ++nt) {
            int row = wn + nt * 16 + ln;
            #pragma unroll
            for (int h = 0; h < 2; ++h) {
                int cc = (h * 4 + quad) ^ (ln & 7);
                bff[nt][h] = *(const bf16x8*)&Bs[row * 64 + cc * 8];
            }
        }
        #pragma unroll
        for (int mt = 0; mt < 4; ++mt)
            #pragma unroll
            for (int nt = 0; nt < 4; ++nt) {
                acc[mt][nt] = __builtin_amdgcn_mfma_f32_16x16x32_bf16(af[mt][0], bff[nt][0], acc[mt][nt], 0, 0, 0);
                acc[mt][nt] = __builtin_amdgcn_mfma_f32_16x16x32_bf16(af[mt][1], bff[nt][1], acc[mt][nt], 0, 0, 0);
            }
    }

    if (isQK) {
        __bf16* out = qkT + (size_t)b * HW * 1024;
        float bcol[4], scol[4];
        #pragma unroll
        for (int nt = 0; nt < 4; ++nt) {
            int col = bn + wn + nt * 16 + ln;
            bcol[nt] = bias[col];
            scol[nt] = (col < 512) ? scaleLo : 1.0f;
        }
        #pragma unroll
        for (int mt = 0; mt < 4; ++mt)
            #pragma unroll
            for (int r = 0; r < 4; ++r) {
                int row = bm + wm + mt * 16 + quad * 4 + r;
                #pragma unroll
                for (int nt = 0; nt < 4; ++nt) {
                    int col = bn + wn + nt * 16 + ln;
                    out[(size_t)row * 1024 + col] = (__bf16)((acc[mt][nt][r] + bcol[nt]) * scol[nt]);
                }
            }
    } else {
        __bf16* out = vbuf + (size_t)b * Cc * HW;
        #pragma unroll
        for (int mt = 0; mt < 4; ++mt)
            #pragma unroll
            for (int r = 0; r < 4; ++r) {
                int row = bm + wm + mt * 16 + quad * 4 + r;
                float brow = bias[1024 + row];
                #pragma unroll
                for (int nt = 0; nt < 4; ++nt) {
                    int col = bn + wn + nt * 16 + ln;
                    out[(size_t)row * 1024 + col] = (__bf16)(acc[mt][nt][r] + brow);
                }
            }
    }
}

// ---------------- proj GEMM 64x128 tiles with fp32 residual epilogue ----------------
__global__ __launch_bounds__(256) void proj_gemm(
    const __bf16* __restrict__ wp, const __bf16* __restrict__ attnT,
    const float* __restrict__ bias, const float* __restrict__ resid,
    float* __restrict__ outp) {
    __shared__ __align__(16) __bf16 As[64 * 64];
    __shared__ __align__(16) __bf16 Bs[128 * 64];
    int tid = threadIdx.x;
    int wv = tid >> 6, lane = tid & 63, ln = lane & 15, quad = lane >> 4;
    int b = blockIdx.z;
    int bm = blockIdx.y * 64, bn = blockIdx.x * 128;
    const __bf16* Qb = attnT + (size_t)b * HW * Cc;
    int wm = (wv >> 1) * 32, wn = (wv & 1) * 64;

    f32x4 acc[2][4];
    #pragma unroll
    for (int i = 0; i < 2; ++i)
        #pragma unroll
        for (int j = 0; j < 4; ++j) acc[i][j] = (f32x4){0.f, 0.f, 0.f, 0.f};

    for (int k0 = 0; k0 < 512; k0 += 64) {
        __syncthreads();
        #pragma unroll
        for (int u = 0; u < 2; ++u) {
            int idx = u * 256 + tid;
            int r = idx >> 3, lc = idx & 7;
            int cg = lc ^ (r & 7);
            async16(wp + (size_t)(bm + r) * 512 + k0 + cg * 8, &As[r * 64 + lc * 8]);
        }
        #pragma unroll
        for (int u = 0; u < 4; ++u) {
            int idx = u * 256 + tid;
            int r = idx >> 3, lc = idx & 7;
            int cg = lc ^ (r & 7);
            async16(Qb + (size_t)(bn + r) * 512 + k0 + cg * 8, &Bs[r * 64 + lc * 8]);
        }
        __syncthreads();
        bf16x8 af[2][2], bff[4][2];
        #pragma unroll
        for (int mt = 0; mt < 2; ++mt) {
            int row = wm + mt * 16 + ln;
            #pragma unroll
            for (int h = 0; h < 2; ++h) {
                int cc = (h * 4 + quad) ^ (ln & 7);
                af[mt][h] = *(const bf16x8*)&As[row * 64 + cc * 8];
            }
        }
        #pragma unroll
        for (int nt = 0; nt < 4; ++nt) {
            int row = wn + nt * 16 + ln;
            #pragma unroll
            for (int h = 0; h < 2; ++h) {
                int cc = (h * 4 + quad) ^ (ln & 7);
                bff[nt][h] = *(const bf16x8*)&Bs[row * 64 + cc * 8];
            }
        }
        #pragma unroll
        for (int mt = 0; mt < 2; ++mt)
            #pragma unroll
            for (int nt = 0; nt < 4; ++nt) {
                acc[mt][nt] = __builtin_amdgcn_mfma_f32_16x16x32_bf16(af[mt][0], bff[nt][0], acc[mt][nt], 0, 0, 0);
                acc[mt][nt] = __builtin_amdgcn_mfma_f32_16x16x32_bf16(af[mt][1], bff[nt][1], acc[mt][nt], 0, 0, 0);
            }
    }

    float* out = outp + (size_t)b * Cc * HW;
    const float* res = resid + (size_t)b * Cc * HW;
    #pragma unroll
    for (int mt = 0; mt < 2; ++mt)
        #pragma unroll
        for (int r = 0; r < 4; ++r) {
            int row = bm + wm + mt * 16 + quad * 4 + r;
            float bv = bias[row];
            #pragma unroll
            for (int nt = 0; nt < 4; ++nt) {
                int col = bn + wn + nt * 16 + ln;
                size_t idx = (size_t)row * 1024 + col;
                out[idx] = acc[mt][nt][r] + bv + res[idx];
            }
        }
}

// ---------------- Flash attention: 128 q/block (2 strips/wave), 128 keys/barrier ----------------
// Grid (h=8, qb=8, b=8): idx%8 == h -> per-head XCD L2 locality.
// Max-free softmax: Q pre-scaled by 0.125*log2e; p = v_exp_f32(s); P packed via v_perm.
__global__ __launch_bounds__(256) void attn_mfma(const __bf16* __restrict__ qkT,
                                                 const __bf16* __restrict__ vbuf,
                                                 __bf16* __restrict__ attnT) {
    __shared__ __align__(16) __bf16 Ks[2][64 * 64];
    __shared__ __align__(16) __bf16 Vs[2][64 * 64];
    int tid = threadIdx.x;
    int wv = tid >> 6, lane = tid & 63, ln = lane & 15, quad = lane >> 4;
    int h = blockIdx.x, b = blockIdx.z;
    int i0 = blockIdx.y * 128 + wv * 32;

    const __bf16* qbase = qkT + ((size_t)b * HW + i0 + ln) * 1024 + h * HD + quad * 8;
    bf16x8 qf[2][2];
    #pragma unroll
    for (int mt = 0; mt < 2; ++mt) {
        qf[mt][0] = *(const bf16x8*)(qbase + (size_t)mt * 16 * 1024);
        qf[mt][1] = *(const bf16x8*)(qbase + (size_t)mt * 16 * 1024 + 32);
    }

    f32x4 oacc[2][4];
    #pragma unroll
    for (int mt = 0; mt < 2; ++mt)
        #pragma unroll
        for (int ct = 0; ct < 4; ++ct) oacc[mt][ct] = (f32x4){0.f, 0.f, 0.f, 0.f};
    float lsum[2] = {0.f, 0.f};

    for (int kt = 0; kt < 8; ++kt) {        // 8 barrier phases, 128 keys each
        __syncthreads();
        #pragma unroll
        for (int hh = 0; hh < 2; ++hh) {
            int kb = kt * 128 + hh * 64;
            #pragma unroll
            for (int u = 0; u < 2; ++u) {
                int idx = u * 256 + tid;
                int r = idx >> 3, lc = idx & 7;
                int cg = lc ^ (r & 7);
                async16(qkT + ((size_t)b * HW + kb + r) * 1024 + 512 + h * HD + cg * 8,
                        &Ks[hh][idx * 8]);
                async16(vbuf + ((size_t)b * Cc + h * HD + r) * HW + kb + cg * 8,
                        &Vs[hh][idx * 8]);
            }
        }
        __syncthreads();

        #pragma unroll
        for (int hh = 0; hh < 2; ++hh) {
            f32x4 st[2][4];
            #pragma unroll
            for (int jt = 0; jt < 4; ++jt) {
                int row = jt * 16 + ln;
                int c0 = quad ^ (ln & 7);
                int c1 = (4 + quad) ^ (ln & 7);
                bf16x8 kf0 = *(const bf16x8*)&Ks[hh][row * 64 + c0 * 8];
                bf16x8 kf1 = *(const bf16x8*)&Ks[hh][row * 64 + c1 * 8];
                #pragma unroll
                for (int mt = 0; mt < 2; ++mt) {
                    f32x4 s = (f32x4){0.f, 0.f, 0.f, 0.f};
                    s = __builtin_amdgcn_mfma_f32_16x16x32_bf16(kf0, qf[mt][0], s, 0, 0, 0);
                    s = __builtin_amdgcn_mfma_f32_16x16x32_bf16(kf1, qf[mt][1], s, 0, 0, 0);
                    st[mt][jt] = s;
                }
            }

            bf16x4 pk[2][4];
            #pragma unroll
            for (int mt = 0; mt < 2; ++mt)
                #pragma unroll
                for (int jt = 0; jt < 4; ++jt) {
                    float p0 = __builtin_amdgcn_exp2f(st[mt][jt][0]);
                    float p1 = __builtin_amdgcn_exp2f(st[mt][jt][1]);
                    float p2 = __builtin_amdgcn_exp2f(st[mt][jt][2]);
                    float p3 = __builtin_amdgcn_exp2f(st[mt][jt][3]);
                    lsum[mt] += (p0 + p1) + (p2 + p3);
                    u32x2 w = { pk_bf16(p1, p0), pk_bf16(p3, p2) };
                    pk[mt][jt] = __builtin_bit_cast(bf16x4, w);
                }

            #pragma unroll
            for (int ct = 0; ct < 4; ++ct) {
                int row = ct * 16 + ln;
                bf16x4 vf[4];
                #pragma unroll
                for (int kss = 0; kss < 4; ++kss) {
                    int cc16 = (kss * 2 + (quad >> 1)) ^ (ln & 7);
                    vf[kss] = *(const bf16x4*)&Vs[hh][row * 64 + cc16 * 8 + (quad & 1) * 4];
                }
                #pragma unroll
                for (int mt = 0; mt < 2; ++mt)
                    #pragma unroll
                    for (int kss = 0; kss < 4; ++kss)
                        oacc[mt][ct] = mfma16(vf[kss], pk[mt][kss], oacc[mt][ct]);
            }
        }
    }

    #pragma unroll
    for (int mt = 0; mt < 2; ++mt) {
        lsum[mt] += __shfl_xor(lsum[mt], 16);
        lsum[mt] += __shfl_xor(lsum[mt], 32);
        float rl = 1.f / lsum[mt];
        __bf16* op = attnT + ((size_t)b * HW + i0 + mt * 16 + ln) * Cc + h * HD + quad * 4;
        #pragma unroll
        for (int ct = 0; ct < 4; ++ct) {
            bf16x4 o = { (__bf16)(oacc[mt][ct][0] * rl), (__bf16)(oacc[mt][ct][1] * rl),
                         (__bf16)(oacc[mt][ct][2] * rl), (__bf16)(oacc[mt][ct][3] * rl) };
            *(bf16x4*)(op + ct * 16) = o;
        }
    }
}

extern "C" void kernel_launch(void* const* d_in, const int* in_sizes, int n_in,
                              void* d_out, int out_size, void* d_ws, size_t ws_size,
                              hipStream_t stream) {
    const float* x      = (const float*)d_in[0];
    const float* gamma  = (const float*)d_in[1];
    const float* beta   = (const float*)d_in[2];
    const float* w_qkv  = (const float*)d_in[3];
    const float* b_qkv  = (const float*)d_in[4];
    const float* w_proj = (const float*)d_in[5];
    const float* b_proj = (const float*)d_in[6];
    float* out = (float*)d_out;

    __bf16* wq_bf  = (__bf16*)d_ws;
    __bf16* wp_bf  = wq_bf + (size_t)1536 * 512;
    __bf16* hnT    = wp_bf + (size_t)512 * 512;
    __bf16* qkT    = hnT + (size_t)Bn * HW * Cc;
    __bf16* vbuf   = qkT + (size_t)Bn * HW * 1024;
    __bf16* attnT  = vbuf + (size_t)Bn * Cc * HW;

    gn_fused<<<1280, 256, 0, stream>>>(x, gamma, beta, hnT, w_qkv, wq_bf, w_proj, wp_bf);

    const float QSCALE = 0.125f * 1.44269504088896f;  // hd^-0.5 * log2(e)
    dim3 gqkv(8, 12, Bn);
    qkv_gemm<<<gqkv, 256, 0, stream>>>(hnT, wq_bf, b_qkv, qkT, vbuf, QSCALE);

    dim3 ga(8, 8, 8);       // (h, qb, b): idx%8 == h -> per-head XCD locality
    attn_mfma<<<ga, 256, 0, stream>>>(qkT, vbuf, attnT);

    dim3 gp(8, 8, Bn);
    proj_gemm<<<gp, 256, 0, stream>>>(wp_bf, attnT, b_proj, x, out);
}

// Round 14
// 136.178 us; speedup vs baseline: 1.2045x; 1.0720x over previous
//
#include <hip/hip_runtime.h>
#include <hip/hip_cooperative_groups.h>
#include <math.h>

namespace cg = cooperative_groups;

#define Bn 8
#define Cc 512
#define HW 1024
#define HEADS 8
#define HD 64
#define GROUPS 32
#define CPG 16
#define EPS 1e-5f

typedef float f32x4 __attribute__((ext_vector_type(4)));
typedef __bf16 bf16x8 __attribute__((ext_vector_type(8)));
typedef __bf16 bf16x4 __attribute__((ext_vector_type(4)));
typedef short s16x4 __attribute__((ext_vector_type(4)));
typedef unsigned u32x2 __attribute__((ext_vector_type(2)));

__device__ __forceinline__ void async16(const __bf16* g, __bf16* l) {
    __builtin_amdgcn_global_load_lds((const __attribute__((address_space(1))) unsigned int*)g,
                                     (__attribute__((address_space(3))) unsigned int*)l, 16, 0, 0);
}

__device__ __forceinline__ f32x4 mfma16(bf16x4 a, bf16x4 b, f32x4 c) {
    return __builtin_amdgcn_mfma_f32_16x16x16bf16_1k(
        __builtin_bit_cast(s16x4, a), __builtin_bit_cast(s16x4, b), c, 0, 0, 0);
}

__device__ __forceinline__ unsigned pk_bf16(float f1, float f0) {
    return __builtin_amdgcn_perm(__builtin_bit_cast(unsigned, f1),
                                 __builtin_bit_cast(unsigned, f0), 0x07060302u);
}

// ---------------- Phase 1: GN (blk<256) + weight conv (blk>=256, 256 blocks) ----------------
// LDS use: exactly 32768 B. Stats aux overlaid on xs[0..19] with register keep/restore.
__device__ __forceinline__ void gn_phase(char* smem, int blk, int tid,
    const float* __restrict__ x, const float* __restrict__ gamma,
    const float* __restrict__ beta, __bf16* __restrict__ hnT,
    const float* __restrict__ wq, __bf16* __restrict__ wq_bf,
    const float* __restrict__ wp, __bf16* __restrict__ wp_bf) {
    if (blk >= 256) {
        int base = (blk - 256) * 1024 + tid;
        #pragma unroll
        for (int u = 0; u < 4; ++u) {
            int i = base + u * 256;
            if (i < 196608) {
                float4 v = ((const float4*)wq)[i];
                bf16x4 o = { (__bf16)v.x, (__bf16)v.y, (__bf16)v.z, (__bf16)v.w };
                ((bf16x4*)wq_bf)[i] = o;
            } else {
                int j = i - 196608;
                float4 v = ((const float4*)wp)[j];
                bf16x4 o = { (__bf16)v.x, (__bf16)v.y, (__bf16)v.z, (__bf16)v.w };
                ((bf16x4*)wp_bf)[j] = o;
            }
        }
        return;
    }
    __bf16* xs = (__bf16*)smem;          // full 32 KB
    float* fs = (float*)smem;            // overlay: fs[0..9] used transiently
    int b = blk >> 5, g = blk & 31;
    const float* xp = x + ((size_t)b * Cc + g * CPG) * HW;

    float s = 0.f, ss = 0.f;
    for (int i4 = tid; i4 < 4096; i4 += 256) {
        float4 v = ((const float4*)xp)[i4];
        s  += (v.x + v.y) + (v.z + v.w);
        ss += (v.x * v.x + v.y * v.y) + (v.z * v.z + v.w * v.w);
        bf16x4 o = { (__bf16)v.x, (__bf16)v.y, (__bf16)v.z, (__bf16)v.w };
        ((bf16x4*)xs)[i4] = o;
    }
    for (int off = 32; off > 0; off >>= 1) {
        s  += __shfl_down(s, off);
        ss += __shfl_down(ss, off);
    }
    int wave = tid >> 6, lane = tid & 63;
    __syncthreads();                      // staging complete
    float keep = 0.f;
    if (tid < 20) keep = (float)xs[tid];  // preserve c=0, n=0..19 (lossless bf16 round-trip)
    __syncthreads();                      // reads done before overlay write
    if (lane == 0) { fs[wave * 2] = s; fs[wave * 2 + 1] = ss; }
    __syncthreads();
    if (tid == 0) {
        float S  = fs[0] + fs[2] + fs[4] + fs[6];
        float SS = fs[1] + fs[3] + fs[5] + fs[7];
        float mean = S / 16384.f;
        float var  = SS / 16384.f - mean * mean;
        fs[8] = mean;
        fs[9] = rsqrtf(var + EPS);
    }
    __syncthreads();
    float mean = fs[8], rstd = fs[9];
    __syncthreads();                      // all read stats before restore
    if (tid < 20) xs[tid] = (__bf16)keep; // restore xs
    __syncthreads();

    float gl[16], bl[16];                 // uniform -> scalar loads
    #pragma unroll
    for (int c = 0; c < 16; ++c) { gl[c] = gamma[g * CPG + c]; bl[c] = beta[g * CPG + c]; }
    #pragma unroll
    for (int u = 0; u < 4; ++u) {
        int n = tid + u * 256;
        union { __bf16 bs[16]; uint4 q[2]; } o;
        #pragma unroll
        for (int c = 0; c < 16; ++c) {
            float v = (float)xs[c * 1024 + n];
            o.bs[c] = (__bf16)((v - mean) * rstd * gl[c] + bl[c]);
        }
        uint4* dst = (uint4*)(hnT + ((size_t)b * HW + n) * Cc + g * CPG);
        dst[0] = o.q[0];
        dst[1] = o.q[1];
    }
}

// ---------------- Phase 2: one 128x128 QKV tile (t in [0,768)) ----------------
__device__ __forceinline__ void qkv_tile(char* smem, int t, int tid,
    const __bf16* __restrict__ hnT, const __bf16* __restrict__ wq,
    const float* __restrict__ bias, __bf16* __restrict__ qkT,
    __bf16* __restrict__ vbuf, float scaleLo) {
    __bf16* As = (__bf16*)smem;
    __bf16* Bs = (__bf16*)(smem + 16384);
    int wv = tid >> 6, lane = tid & 63, ln = lane & 15, quad = lane >> 4;
    int b = t / 96, rem = t % 96;
    int y = rem >> 3, xv = rem & 7;
    bool isQK = y < 8;
    int bm = (isQK ? y : y - 8) * 128;
    int bn = xv * 128;
    const __bf16* hb = hnT + (size_t)b * HW * Cc;
    const __bf16* Pb = isQK ? hb : wq + (size_t)1024 * 512;
    const __bf16* Qb = isQK ? wq : hb;
    int wm = (wv >> 1) * 64, wn = (wv & 1) * 64;

    f32x4 acc[4][4];
    #pragma unroll
    for (int i = 0; i < 4; ++i)
        #pragma unroll
        for (int j = 0; j < 4; ++j) acc[i][j] = (f32x4){0.f, 0.f, 0.f, 0.f};

    for (int k0 = 0; k0 < 512; k0 += 64) {
        __syncthreads();
        #pragma unroll
        for (int u = 0; u < 4; ++u) {
            int idx = u * 256 + tid;
            int r = idx >> 3, lc = idx & 7;
            int cg2 = lc ^ (r & 7);
            async16(Pb + (size_t)(bm + r) * 512 + k0 + cg2 * 8, &As[r * 64 + lc * 8]);
            async16(Qb + (size_t)(bn + r) * 512 + k0 + cg2 * 8, &Bs[r * 64 + lc * 8]);
        }
        __syncthreads();
        bf16x8 af[4][2], bff[4][2];
        #pragma unroll
        for (int mt = 0; mt < 4; ++mt) {
            int row = wm + mt * 16 + ln;
            #pragma unroll
            for (int h = 0; h < 2; ++h) {
                int cc = (h * 4 + quad) ^ (ln & 7);
                af[mt][h] = *(const bf16x8*)&As[row * 64 + cc * 8];
            }
        }
        #pragma unroll
        for (int nt = 0; nt < 4; ++nt) {
            int row = wn + nt * 16 + ln;
            #pragma unroll
            for (int h = 0; h < 2; ++h) {
                int cc = (h * 4 + quad) ^ (ln & 7);
                bff[nt][h] = *(const bf16x8*)&Bs[row * 64 + cc * 8];
            }
        }
        #pragma unroll
        for (int mt = 0; mt < 4; ++mt)
            #pragma unroll
            for (int nt = 0; nt < 4; ++nt) {
                acc[mt][nt] = __builtin_amdgcn_mfma_f32_16x16x32_bf16(af[mt][0], bff[nt][0], acc[mt][nt], 0, 0, 0);
                acc[mt][nt] = __builtin_amdgcn_mfma_f32_16x16x32_bf16(af[mt][1], bff[nt][1], acc[mt][nt], 0, 0, 0);
            }
    }

    if (isQK) {
        __bf16* out = qkT + (size_t)b * HW * 1024;
        float bcol[4], scol[4];
        #pragma unroll
        for (int nt = 0; nt < 4; ++nt) {
            int col = bn + wn + nt * 16 + ln;
            bcol[nt] = bias[col];
            scol[nt] = (col < 512) ? scaleLo : 1.0f;
        }
        #pragma unroll
        for (int mt = 0; mt < 4; ++mt)
            #pragma unroll
            for (int r = 0; r < 4; ++r) {
                int row = bm + wm + mt * 16 + quad * 4 + r;
                #pragma unroll
                for (int nt = 0; nt < 4; ++nt) {
                    int col = bn + wn + nt * 16 + ln;
                    out[(size_t)row * 1024 + col] = (__bf16)((acc[mt][nt][r] + bcol[nt]) * scol[nt]);
                }
            }
    } else {
        __bf16* out = vbuf + (size_t)b * Cc * HW;
        #pragma unroll
        for (int mt = 0; mt < 4; ++mt)
            #pragma unroll
            for (int r = 0; r < 4; ++r) {
                int row = bm + wm + mt * 16 + quad * 4 + r;
                float brow = bias[1024 + row];
                #pragma unroll
                for (int nt = 0; nt < 4; ++nt) {
                    int col = bn + wn + nt * 16 + ln;
                    out[(size_t)row * 1024 + col] = (__bf16)(acc[mt][nt][r] + brow);
                }
            }
    }
}

// ---------------- Phase 3: flash attention unit (128 q, 128 keys/barrier) ----------------
__device__ __forceinline__ void attn_unit(char* smem, int blk, int tid,
    const __bf16* __restrict__ qkT, const __bf16* __restrict__ vbuf,
    __bf16* __restrict__ attnT) {
    __bf16* Ks = (__bf16*)smem;
    __bf16* Vs = (__bf16*)(smem + 16384);
    int wv = tid >> 6, lane = tid & 63, ln = lane & 15, quad = lane >> 4;
    int h = blk & 7, qb = (blk >> 3) & 7, b = blk >> 6;
    int i0 = qb * 128 + wv * 32;

    const __bf16* qbase = qkT + ((size_t)b * HW + i0 + ln) * 1024 + h * HD + quad * 8;
    bf16x8 qf[2][2];
    #pragma unroll
    for (int mt = 0; mt < 2; ++mt) {
        qf[mt][0] = *(const bf16x8*)(qbase + (size_t)mt * 16 * 1024);
        qf[mt][1] = *(const bf16x8*)(qbase + (size_t)mt * 16 * 1024 + 32);
    }

    f32x4 oacc[2][4];
    #pragma unroll
    for (int mt = 0; mt < 2; ++mt)
        #pragma unroll
        for (int ct = 0; ct < 4; ++ct) oacc[mt][ct] = (f32x4){0.f, 0.f, 0.f, 0.f};
    float lsum[2] = {0.f, 0.f};

    for (int kt = 0; kt < 8; ++kt) {
        __syncthreads();
        #pragma unroll
        for (int hh = 0; hh < 2; ++hh) {
            int kb = kt * 128 + hh * 64;
            #pragma unroll
            for (int u = 0; u < 2; ++u) {
                int idx = u * 256 + tid;
                int r = idx >> 3, lc = idx & 7;
                int cg2 = lc ^ (r & 7);
                async16(qkT + ((size_t)b * HW + kb + r) * 1024 + 512 + h * HD + cg2 * 8,
                        &Ks[hh * 4096 + idx * 8]);
                async16(vbuf + ((size_t)b * Cc + h * HD + r) * HW + kb + cg2 * 8,
                        &Vs[hh * 4096 + idx * 8]);
            }
        }
        __syncthreads();

        #pragma unroll
        for (int hh = 0; hh < 2; ++hh) {
            f32x4 st[2][4];
            #pragma unroll
            for (int jt = 0; jt < 4; ++jt) {
                int row = jt * 16 + ln;
                int c0 = quad ^ (ln & 7);
                int c1 = (4 + quad) ^ (ln & 7);
                bf16x8 kf0 = *(const bf16x8*)&Ks[hh * 4096 + row * 64 + c0 * 8];
                bf16x8 kf1 = *(const bf16x8*)&Ks[hh * 4096 + row * 64 + c1 * 8];
                #pragma unroll
                for (int mt = 0; mt < 2; ++mt) {
                    f32x4 s = (f32x4){0.f, 0.f, 0.f, 0.f};
                    s = __builtin_amdgcn_mfma_f32_16x16x32_bf16(kf0, qf[mt][0], s, 0, 0, 0);
                    s = __builtin_amdgcn_mfma_f32_16x16x32_bf16(kf1, qf[mt][1], s, 0, 0, 0);
                    st[mt][jt] = s;
                }
            }

            bf16x4 pk[2][4];
            #pragma unroll
            for (int mt = 0; mt < 2; ++mt)
                #pragma unroll
                for (int jt = 0; jt < 4; ++jt) {
                    float p0 = __builtin_amdgcn_exp2f(st[mt][jt][0]);
                    float p1 = __builtin_amdgcn_exp2f(st[mt][jt][1]);
                    float p2 = __builtin_amdgcn_exp2f(st[mt][jt][2]);
                    float p3 = __builtin_amdgcn_exp2f(st[mt][jt][3]);
                    lsum[mt] += (p0 + p1) + (p2 + p3);
                    u32x2 w = { pk_bf16(p1, p0), pk_bf16(p3, p2) };
                    pk[mt][jt] = __builtin_bit_cast(bf16x4, w);
                }

            #pragma unroll
            for (int ct = 0; ct < 4; ++ct) {
                int row = ct * 16 + ln;
                bf16x4 vf[4];
                #pragma unroll
                for (int kss = 0; kss < 4; ++kss) {
                    int cc16 = (kss * 2 + (quad >> 1)) ^ (ln & 7);
                    vf[kss] = *(const bf16x4*)&Vs[hh * 4096 + row * 64 + cc16 * 8 + (quad & 1) * 4];
                }
                #pragma unroll
                for (int mt = 0; mt < 2; ++mt)
                    #pragma unroll
                    for (int kss = 0; kss < 4; ++kss)
                        oacc[mt][ct] = mfma16(vf[kss], pk[mt][kss], oacc[mt][ct]);
            }
        }
    }

    #pragma unroll
    for (int mt = 0; mt < 2; ++mt) {
        lsum[mt] += __shfl_xor(lsum[mt], 16);
        lsum[mt] += __shfl_xor(lsum[mt], 32);
        float rl = 1.f / lsum[mt];
        __bf16* op = attnT + ((size_t)b * HW + i0 + mt * 16 + ln) * Cc + h * HD + quad * 4;
        #pragma unroll
        for (int ct = 0; ct < 4; ++ct) {
            bf16x4 o = { (__bf16)(oacc[mt][ct][0] * rl), (__bf16)(oacc[mt][ct][1] * rl),
                         (__bf16)(oacc[mt][ct][2] * rl), (__bf16)(oacc[mt][ct][3] * rl) };
            *(bf16x4*)(op + ct * 16) = o;
        }
    }
}

// ---------------- Phase 4: proj 64x128 tile with fp32 residual epilogue ----------------
__device__ __forceinline__ void proj_unit(char* smem, int blk, int tid,
    const __bf16* __restrict__ wp, const __bf16* __restrict__ attnT,
    const float* __restrict__ bias, const float* __restrict__ resid,
    float* __restrict__ outp) {
    __bf16* As = (__bf16*)smem;
    __bf16* Bs = (__bf16*)(smem + 8192);
    int wv = tid >> 6, lane = tid & 63, ln = lane & 15, quad = lane >> 4;
    int xv = blk & 7, y = (blk >> 3) & 7, b = blk >> 6;
    int bm = y * 64, bn = xv * 128;
    const __bf16* Qb = attnT + (size_t)b * HW * Cc;
    int wm = (wv >> 1) * 32, wn = (wv & 1) * 64;

    f32x4 acc[2][4];
    #pragma unroll
    for (int i = 0; i < 2; ++i)
        #pragma unroll
        for (int j = 0; j < 4; ++j) acc[i][j] = (f32x4){0.f, 0.f, 0.f, 0.f};

    for (int k0 = 0; k0 < 512; k0 += 64) {
        __syncthreads();
        #pragma unroll
        for (int u = 0; u < 2; ++u) {
            int idx = u * 256 + tid;
            int r = idx >> 3, lc = idx & 7;
            int cg2 = lc ^ (r & 7);
            async16(wp + (size_t)(bm + r) * 512 + k0 + cg2 * 8, &As[r * 64 + lc * 8]);
        }
        #pragma unroll
        for (int u = 0; u < 4; ++u) {
            int idx = u * 256 + tid;
            int r = idx >> 3, lc = idx & 7;
            int cg2 = lc ^ (r & 7);
            async16(Qb + (size_t)(bn + r) * 512 + k0 + cg2 * 8, &Bs[r * 64 + lc * 8]);
        }
        __syncthreads();
        bf16x8 af[2][2], bff[4][2];
        #pragma unroll
        for (int mt = 0; mt < 2; ++mt) {
            int row = wm + mt * 16 + ln;
            #pragma unroll
            for (int h = 0; h < 2; ++h) {
                int cc = (h * 4 + quad) ^ (ln & 7);
                af[mt][h] = *(const bf16x8*)&As[row * 64 + cc * 8];
            }
        }
        #pragma unroll
        for (int nt = 0; nt < 4; ++nt) {
            int row = wn + nt * 16 + ln;
            #pragma unroll
            for (int h = 0; h < 2; ++h) {
                int cc = (h * 4 + quad) ^ (ln & 7);
                bff[nt][h] = *(const bf16x8*)&Bs[row * 64 + cc * 8];
            }
        }
        #pragma unroll
        for (int mt = 0; mt < 2; ++mt)
            #pragma unroll
            for (int nt = 0; nt < 4; ++nt) {
                acc[mt][nt] = __builtin_amdgcn_mfma_f32_16x16x32_bf16(af[mt][0], bff[nt][0], acc[mt][nt], 0, 0, 0);
                acc[mt][nt] = __builtin_amdgcn_mfma_f32_16x16x32_bf16(af[mt][1], bff[nt][1], acc[mt][nt], 0, 0, 0);
            }
    }

    float* out = outp + (size_t)b * Cc * HW;
    const float* res = resid + (size_t)b * Cc * HW;
    #pragma unroll
    for (int mt = 0; mt < 2; ++mt)
        #pragma unroll
        for (int r = 0; r < 4; ++r) {
            int row = bm + wm + mt * 16 + quad * 4 + r;
            float bv = bias[row];
            #pragma unroll
            for (int nt = 0; nt < 4; ++nt) {
                int col = bn + wn + nt * 16 + ln;
                size_t idx = (size_t)row * 1024 + col;
                out[idx] = acc[mt][nt][r] + bv + res[idx];
            }
        }
}

// ---------------- Mega kernel (cooperative): all phases, grid sync between ----------------
__global__ __launch_bounds__(256, 2) void mega(
    const float* __restrict__ x, const float* __restrict__ gamma,
    const float* __restrict__ beta,
    const float* __restrict__ wq_f, const float* __restrict__ wp_f,
    const float* __restrict__ bq, const float* __restrict__ bp,
    __bf16* wq_bf, __bf16* wp_bf, __bf16* hnT, __bf16* qkT,
    __bf16* vbuf, __bf16* attnT, float* out, float qscale) {
    __shared__ __align__(16) char smem[32768];
    int blk = blockIdx.x, tid = threadIdx.x;
    cg::grid_group grid = cg::this_grid();

    gn_phase(smem, blk, tid, x, gamma, beta, hnT, wq_f, wq_bf, wp_f, wp_bf);
    grid.sync();
    for (int t = blk; t < 768; t += 512)
        qkv_tile(smem, t, tid, hnT, wq_bf, bq, qkT, vbuf, qscale);
    grid.sync();
    attn_unit(smem, blk, tid, qkT, vbuf, attnT);
    grid.sync();
    proj_unit(smem, blk, tid, wp_bf, attnT, bp, x, out);
}

// ---------------- Fallback kernels (same phase code, 4 regular launches) ----------------
__global__ __launch_bounds__(256, 2) void gn_k(
    const float* x, const float* gamma, const float* beta, __bf16* hnT,
    const float* wq, __bf16* wq_bf, const float* wp, __bf16* wp_bf) {
    __shared__ __align__(16) char smem[32768];
    gn_phase(smem, blockIdx.x, threadIdx.x, x, gamma, beta, hnT, wq, wq_bf, wp, wp_bf);
}
__global__ __launch_bounds__(256, 2) void qkv_k(
    const __bf16* hnT, const __bf16* wq, const float* bq,
    __bf16* qkT, __bf16* vbuf, float qscale) {
    __shared__ __align__(16) char smem[32768];
    qkv_tile(smem, blockIdx.x, threadIdx.x, hnT, wq, bq, qkT, vbuf, qscale);
}
__global__ __launch_bounds__(256, 2) void attn_k(
    const __bf16* qkT, const __bf16* vbuf, __bf16* attnT) {
    __shared__ __align__(16) char smem[32768];
    attn_unit(smem, blockIdx.x, threadIdx.x, qkT, vbuf, attnT);
}
__global__ __launch_bounds__(256, 2) void proj_k(
    const __bf16* wp, const __bf16* attnT, const float* bp,
    const float* resid, float* out) {
    __shared__ __align__(16) char smem[32768];
    proj_unit(smem, blockIdx.x, threadIdx.x, wp, attnT, bp, resid, out);
}

extern "C" void kernel_launch(void* const* d_in, const int* in_sizes, int n_in,
                              void* d_out, int out_size, void* d_ws, size_t ws_size,
                              hipStream_t stream) {
    const float* x      = (const float*)d_in[0];
    const float* gamma  = (const float*)d_in[1];
    const float* beta   = (const float*)d_in[2];
    const float* w_qkv  = (const float*)d_in[3];
    const float* b_qkv  = (const float*)d_in[4];
    const float* w_proj = (const float*)d_in[5];
    const float* b_proj = (const float*)d_in[6];
    float* out = (float*)d_out;

    __bf16* wq_bf  = (__bf16*)d_ws;
    __bf16* wp_bf  = wq_bf + (size_t)1536 * 512;
    __bf16* hnT    = wp_bf + (size_t)512 * 512;
    __bf16* qkT    = hnT + (size_t)Bn * HW * Cc;
    __bf16* vbuf   = qkT + (size_t)Bn * HW * 1024;
    __bf16* attnT  = vbuf + (size_t)Bn * Cc * HW;

    float qscale = 0.125f * 1.44269504088896f;   // hd^-0.5 * log2(e)

    // Host-side gate (capture-safe, deterministic): cooperative support + co-residency.
    int dev = 0;
    hipGetDevice(&dev);
    int coop = 0, ncu = 0, maxBlk = 0;
    hipDeviceGetAttribute(&coop, hipDeviceAttributeCooperativeLaunch, dev);
    hipDeviceGetAttribute(&ncu, hipDeviceAttributeMultiprocessorCount, dev);
    hipOccupancyMaxActiveBlocksPerMultiprocessor(&maxBlk, mega, 256, 0);
    bool useCoop = coop && ((long)maxBlk * (long)ncu >= 512);

    hipError_t err = hipErrorUnknown;
    if (useCoop) {
        void* args[] = { (void*)&x, (void*)&gamma, (void*)&beta,
                         (void*)&w_qkv, (void*)&w_proj, (void*)&b_qkv, (void*)&b_proj,
                         (void*)&wq_bf, (void*)&wp_bf, (void*)&hnT, (void*)&qkT,
                         (void*)&vbuf, (void*)&attnT, (void*)&out, (void*)&qscale };
        err = hipLaunchCooperativeKernel((const void*)mega, dim3(512), dim3(256),
                                         args, 0, stream);
    }
    if (err != hipSuccess) {
        gn_k<<<512, 256, 0, stream>>>(x, gamma, beta, hnT, w_qkv, wq_bf, w_proj, wp_bf);
        qkv_k<<<768, 256, 0, stream>>>(hnT, wq_bf, b_qkv, qkT, vbuf, qscale);
        attn_k<<<512, 256, 0, stream>>>(qkT, vbuf, attnT);
        proj_k<<<512, 256, 0, stream>>>(wp_bf, attnT, b_proj, x, out);
    }
}